// Round 1
// baseline (152.838 us; speedup 1.0000x reference)
//
#include <hip/hip_runtime.h>

#define BATCH 32
#define NOBJ  64
#define PADK  264   // halfs; A-tile row stride 528 B (16B-aligned)

typedef _Float16 f16x2 __attribute__((ext_vector_type(2)));
typedef __fp16   h16x2 __attribute__((ext_vector_type(2)));
typedef _Float16 f16x4 __attribute__((ext_vector_type(4)));
typedef _Float16 f16x8 __attribute__((ext_vector_type(8)));
typedef float    f32x4 __attribute__((ext_vector_type(4)));
typedef float    f32x16 __attribute__((ext_vector_type(16)));

#define MFMA32(a, b, c) __builtin_amdgcn_mfma_f32_32x32x16_f16((a), (b), (c), 0, 0, 0)

// ---------------------------------------------------------------------------
// Layer-0 is removed from the MFMA loop entirely (exact algebra):
//   h1[b][(i,j)][n] = relu( h0j[b][j][n] + cib[b][i][n] )
//   h0j = x_j·W0[0:64] + j·W0[64]          (per-batch, shared by all i)
//   cib = x_i·W0[65:193] + i·W0[193] + b1  (per-(b,i))
// Both fp32, computed in prep_all. g_mlp builds act1 directly and runs
// layers 1-3 (K=256, 16 steps each).
//
// Activation LDS layout after layer-1/2 epilogues: physical col
// p = 64*nq + 2*c + ns holds logical col n = 64*nq + 32*ns + c (f16x2 pack).
// Layer-2/3 weight k-order: klog(p) = 64*(p>>6) + 32*(p&1) + ((p&63)>>1).
// Layer-1 weights use identity k-order (act1 is built in plain layout).
//
// R0 (this round): g_mlp_pool widened 256->512 threads (8 waves,
// Mt=2 x Nt=2 per wave). Same 67.6KB LDS tile -> still 2 blocks/CU, but
// 16 waves/CU = 4 waves/SIMD (was 2). acc halves to 64 VGPR/wave ->
// __launch_bounds__(512,4) pins <=128 VGPR. Pipe ratios per CU unchanged
// (LDS ~256cyc vs MFMA 512cyc per k-step) -> MFMA pipe can fill.
// prep_all GEMV loops vectorized to ds_read_b128 (4x fewer LDS instrs).
//
// Dispatches (3): prep_all (800 blocks), g_mlp_pool (1024x512), f_mlp (32).
// NO device-scope fences anywhere (r10 lesson: __threadfence = L2 flush).
// do_layer16 = simple in-loop form (explicit dbuf regressed: m131-m141
// precedent — compiler scheduling already optimal for this structure).
// ---------------------------------------------------------------------------

// ---------------------------------------------------------------------------
// Kernel 0: prep_all.
// blk 0..31  : zero xg; repack weights l=blk>>3 in MFMA B-fragment order
//              (skip l==0 -- unused):
//              wtf[l][ngrp=8][kk=16][lane=64][j=8] = W_l[klog][nlog]
//              nlog = ngrp*32+(lane&31), kphys = kk*16+(lane>>5)*8+j
//              l==1: klog = kphys; l>=2: 2-col interleave mapping.
// blk 32..543: cib (per-(b, 4 i's)); thread t = col n.
// blk 544..799: h0j (per-(b, 8 j's)); thread t = col n.
// ---------------------------------------------------------------------------
__global__ __launch_bounds__(256) void prep_all(
    const float* __restrict__ x_aux,
    const float* __restrict__ g1w, const float* __restrict__ g1b,
    const float* __restrict__ g2w, const float* __restrict__ g3w,
    const float* __restrict__ g4w,
    _Float16* __restrict__ wtf, float* __restrict__ xg,
    float* __restrict__ cib, float* __restrict__ h0j) {
  __shared__ __align__(16) _Float16 tile[256][33];
  const int blk = blockIdx.x;
  const int t = threadIdx.x;

  if (blk < 32) {
    xg[blk * 256 + t] = 0.0f;
    const int l = blk >> 3;
    if (l == 0) return;                 // layer-0 weights not needed
    const int nt = blk & 7;
    const float* src = (l == 1) ? g2w : (l == 2) ? g3w : g4w;

    const int nn = t & 31, kb = t >> 5;
#pragma unroll 4
    for (int pass = 0; pass < 32; ++pass) {
      int kp = pass * 8 + kb;
      int kl = (l == 1) ? kp
                        : 64 * (kp >> 6) + 32 * (kp & 1) + ((kp & 63) >> 1);
      tile[kp][nn] = (_Float16)src[(size_t)kl * 256 + nt * 32 + nn];
    }
    __syncthreads();

    const int lane = t & 63;
    const int nfrag = lane & 31;
    const int kbase = (lane >> 5) * 8;
    _Float16* dst = wtf + ((size_t)(l * 8 + nt) * 16) * 512;
#pragma unroll
    for (int q = 0; q < 4; ++q) {
      int kk = (t >> 6) + 4 * q;
      f16x8 fr;
#pragma unroll
      for (int j = 0; j < 8; ++j)
        fr[j] = tile[kk * 16 + kbase + j][nfrag];
      *(f16x8*)(dst + (size_t)kk * 512 + lane * 8) = fr;
    }
  } else if (blk < 544) {
    // ---- cib = x_i . W0[65:193] + i*W0[193] + b1  (fp32) ----
    float* xs = (float*)&tile[0][0];     // [4][128]
    const int blkc = blk - 32;           // 512 = 32 b x 16 groups
    const int b  = blkc >> 4;
    const int i0 = (blkc & 15) * 4;

#pragma unroll
    for (int u = 0; u < 2; ++u) {
      int idx = u * 256 + t;
      int j = idx >> 7, k = idx & 127;
      xs[j * 128 + k] = x_aux[((size_t)(b * NOBJ + i0 + j)) * 128 + k];
    }
    __syncthreads();

    float c0 = 0.f, c1 = 0.f, c2 = 0.f, c3 = 0.f;
#pragma unroll 2
    for (int k = 0; k < 128; k += 4) {
      f32x4 x0 = *(const f32x4*)&xs[k];
      f32x4 x1 = *(const f32x4*)&xs[128 + k];
      f32x4 x2 = *(const f32x4*)&xs[256 + k];
      f32x4 x3 = *(const f32x4*)&xs[384 + k];
#pragma unroll
      for (int q = 0; q < 4; ++q) {
        float w = g1w[(size_t)(65 + k + q) * 256 + t];
        c0 += x0[q] * w; c1 += x1[q] * w;
        c2 += x2[q] * w; c3 += x3[q] * w;
      }
    }
    float wc = g1w[(size_t)193 * 256 + t];
    float bb = g1b[t];
    c0 += (float)(i0 + 0) * wc + bb;
    c1 += (float)(i0 + 1) * wc + bb;
    c2 += (float)(i0 + 2) * wc + bb;
    c3 += (float)(i0 + 3) * wc + bb;
    cib[((size_t)(b * NOBJ + i0 + 0)) * 256 + t] = c0;
    cib[((size_t)(b * NOBJ + i0 + 1)) * 256 + t] = c1;
    cib[((size_t)(b * NOBJ + i0 + 2)) * 256 + t] = c2;
    cib[((size_t)(b * NOBJ + i0 + 3)) * 256 + t] = c3;
  } else {
    // ---- h0j = x_j . W0[0:64] + j*W0[64]  (fp32, no bias) ----
    // stride-68 rows so f32x4 reads are 16B-aligned; coord handled in regs.
    float* xs = (float*)&tile[0][0];     // [8][68]
    const int blk2 = blk - 544;          // 256 = 32 b x 8 jgroups
    const int b  = blk2 >> 3;
    const int j0 = (blk2 & 7) * 8;

#pragma unroll
    for (int u = 0; u < 2; ++u) {
      int idx = u * 256 + t;             // 0..511
      int jj = idx >> 6, k = idx & 63;
      xs[jj * 68 + k] = x_aux[((size_t)(b * NOBJ + j0 + jj)) * 128 + k];
    }
    __syncthreads();

    float acc[8] = {};
#pragma unroll 2
    for (int k = 0; k < 64; k += 4) {
      f32x4 xv[8];
#pragma unroll
      for (int jj = 0; jj < 8; ++jj)
        xv[jj] = *(const f32x4*)&xs[jj * 68 + k];
#pragma unroll
      for (int q = 0; q < 4; ++q) {
        float w = g1w[(size_t)(k + q) * 256 + t];
#pragma unroll
        for (int jj = 0; jj < 8; ++jj) acc[jj] += xv[jj][q] * w;
      }
    }
    float wc = g1w[(size_t)64 * 256 + t];   // coord column
#pragma unroll
    for (int jj = 0; jj < 8; ++jj)
      h0j[((size_t)(b * NOBJ + j0 + jj)) * 256 + t] =
          acc[jj] + (float)(j0 + jj) * wc;
  }
}

// ---------------------------------------------------------------------------
// One layer GEMM for a wave: Mt=2 M-tiles x Nt=2 N-groups, 16 k-steps.
// Simple in-loop loads (measured best) -- compiler schedules
// lgkmcnt/vmcnt with its own prefetch distance; explicit dbuf regressed.
// acc[idx = m*2 + ns].
// ---------------------------------------------------------------------------
__device__ __forceinline__ void do_layer16(
    const _Float16* __restrict__ bp0, const _Float16* __restrict__ bp1,
    const _Float16* __restrict__ arow, f32x16 acc[4]) {
#pragma unroll
  for (int kk = 0; kk < 16; ++kk) {
    f16x8 b0 = *(const f16x8*)(bp0 + (size_t)kk * 512);
    f16x8 b1 = *(const f16x8*)(bp1 + (size_t)kk * 512);
#pragma unroll
    for (int m = 0; m < 2; ++m) {
      f16x8 a = *(const f16x8*)(arow + (size_t)m * 32 * PADK + kk * 16);
      acc[m * 2]     = MFMA32(a, b0, acc[m * 2]);
      acc[m * 2 + 1] = MFMA32(a, b1, acc[m * 2 + 1]);
    }
  }
}

// ---------------------------------------------------------------------------
// Kernel 1: fused g-MLP layers 1-3 + sum-pool for TWO i's per block.
// Block = 512 thr (8 waves). M=128 (2 i's x 64 j), N=256, K=256.
// Tile build: act1[m][n] = relu(h0j[j] + cib[i]) -- coalesced (1 KB row
// per wave instruction), h0j row read once for both i-halves.
// Wave w: mh = w>>2 picks M-half (m-tiles 2mh,2mh+1), nq = w&3 picks
// N-pair (groups 2nq,2nq+1). acc = 4 x f32x16 = 64 VGPR -> <=128 total,
// 2 blocks/CU = 4 waves/SIMD (was 2: the 37% MfmaUtil plateau).
// ---------------------------------------------------------------------------
__global__ __launch_bounds__(512, 4) void g_mlp_pool(
    const float* __restrict__ h0j,            // [B*64][256] fp32
    const float* __restrict__ cib,            // [B*64][256] fp32
    const _Float16* __restrict__ wtf,         // fragment-ordered
    const float* __restrict__ g2b, const float* __restrict__ g3b,
    const float* __restrict__ g4b,
    float* __restrict__ xg) {                 // [B][256] fp32 (pre-zeroed)
  __shared__ __align__(16) _Float16 As[128][PADK];  // 67.6 KB -> 2 blocks/CU

  const int b  = blockIdx.x >> 5;
  const int i0 = (blockIdx.x & 31) * 2;
  const int t  = threadIdx.x;
  const int lane = t & 63;
  const int wv   = t >> 6;                    // 0..7

  // ---- build act1 tile: rows j and 64+j share the same h0j row ----
  {
    const int c = lane * 4;                   // this lane's 4 cols
    const float* hb = h0j + (size_t)(b * NOBJ) * 256 + c;
    const float* c0p = cib + (size_t)(b * NOBJ + i0) * 256 + c;
    f32x4 cv0 = *(const f32x4*)c0p;
    f32x4 cv1 = *(const f32x4*)(c0p + 256);
#pragma unroll
    for (int it = 0; it < 8; ++it) {
      int j = it * 8 + wv;
      f32x4 hv = *(const f32x4*)(hb + (size_t)j * 256);
      f16x4 p0, p1;
#pragma unroll
      for (int q = 0; q < 4; ++q) {
        p0[q] = (_Float16)fmaxf(hv[q] + cv0[q], 0.f);
        p1[q] = (_Float16)fmaxf(hv[q] + cv1[q], 0.f);
      }
      *(f16x4*)&As[j][c]      = p0;
      *(f16x4*)&As[64 + j][c] = p1;
    }
  }
  __syncthreads();

  const int nq   = wv & 3;          // N-pair (groups 2nq, 2nq+1)
  const int mh   = wv >> 2;         // M-half (m-tiles 2mh, 2mh+1)
  const int c31  = lane & 31;
  const int h    = lane >> 5;       // 0/1
  const int n0   = nq * 64;
  const float* gb[4] = {nullptr, g2b, g3b, g4b};

  for (int layer = 1; layer < 4; ++layer) {
    const float bv0 = gb[layer][n0 + c31];
    const float bv1 = gb[layer][n0 + 32 + c31];

    f32x16 acc[4];   // [m*2 + ns]
#pragma unroll
    for (int x = 0; x < 4; ++x) acc[x] = (f32x16){};

    const _Float16* bp0 =
        wtf + ((size_t)(layer * 8 + nq * 2) * 16) * 512 + lane * 8;
    const _Float16* bp1 = bp0 + 16 * 512;
    const _Float16* arow = &As[c31][h * 8] + (size_t)mh * 64 * PADK;

    do_layer16(bp0, bp1, arow, acc);

    if (layer < 3) {
      __syncthreads();   // all waves done reading As
      // C/D layout: col = lane&31, row = (reg&3) + 8*(reg>>2) + 4*h.
      // Pack both N-streams as f16x2 at phys col 64*nq + 2*c.
      // v_cvt_pkrtz packs in one instruction (values >= 0, RTZ bias ~0).
#pragma unroll
      for (int m = 0; m < 2; ++m)
#pragma unroll
        for (int g = 0; g < 4; ++g)
#pragma unroll
          for (int r = 0; r < 4; ++r) {
            const int row = (mh * 2 + m) * 32 + g * 8 + h * 4 + r;
            const int reg = g * 4 + r;
            h16x2 pk = __builtin_amdgcn_cvt_pkrtz(
                fmaxf(acc[m * 2][reg] + bv0, 0.f),
                fmaxf(acc[m * 2 + 1][reg] + bv1, 0.f));
            *(h16x2*)&As[row][n0 + 2 * c31] = pk;
          }
      __syncthreads();
    } else {
      // layer 4: bias + relu + pool over this wave's 64 rows
      float s0 = 0.f, s1 = 0.f;
#pragma unroll
      for (int m = 0; m < 2; ++m)
#pragma unroll
        for (int reg = 0; reg < 16; ++reg) {
          s0 += fmaxf(acc[m * 2][reg] + bv0, 0.f);
          s1 += fmaxf(acc[m * 2 + 1][reg] + bv1, 0.f);
        }
      s0 += __shfl_xor(s0, 32, 64);   // combine h=0/h=1 row halves
      s1 += __shfl_xor(s1, 32, 64);
      if (h == 0) {
        atomicAdd(&xg[b * 256 + n0 + c31], s0);
        atomicAdd(&xg[b * 256 + n0 + 32 + c31], s1);
      }
    }
  }
}

// ---------------------------------------------------------------------------
// Kernel 2: f-MLP. One block per batch, 1024 threads: n = t&255 owns column,
// kc = t>>8 owns a 64-wide k-chunk; LDS reduce the 4 partials per column.
// ---------------------------------------------------------------------------
__global__ __launch_bounds__(1024) void f_mlp(
    const float* __restrict__ xg,
    const float* __restrict__ f1w, const float* __restrict__ f1b,
    const float* __restrict__ f2w, const float* __restrict__ f2b,
    const float* __restrict__ f3w, const float* __restrict__ f3b,
    float* __restrict__ out) {
  __shared__ float xs[256], ys[256], ps[4][256];
  const int b = blockIdx.x;
  const int t = threadIdx.x;
  const int n = t & 255;
  const int kc = t >> 8;

  if (t < 256) xs[t] = xg[b * 256 + t];
  __syncthreads();

  float p = 0.f;
#pragma unroll 8
  for (int k0 = 0; k0 < 64; ++k0) {
    int k = kc * 64 + k0;
    p += xs[k] * f1w[k * 256 + n];
  }
  ps[kc][n] = p;
  __syncthreads();
  if (t < 256)
    ys[t] = fmaxf(f1b[t] + ps[0][t] + ps[1][t] + ps[2][t] + ps[3][t], 0.f);
  __syncthreads();

  p = 0.f;
#pragma unroll 8
  for (int k0 = 0; k0 < 64; ++k0) {
    int k = kc * 64 + k0;
    p += ys[k] * f2w[k * 256 + n];
  }
  ps[kc][n] = p;
  __syncthreads();
  if (t < 256)
    xs[t] = fmaxf(f2b[t] + ps[0][t] + ps[1][t] + ps[2][t] + ps[3][t], 0.f);
  __syncthreads();

  p = 0.f;
#pragma unroll 8
  for (int k0 = 0; k0 < 64; ++k0) {
    int k = kc * 64 + k0;
    p += xs[k] * f3w[k * 256 + n];
  }
  ps[kc][n] = p;
  __syncthreads();
  if (t < 256)
    out[b * 256 + t] = f3b[t] + ps[0][t] + ps[1][t] + ps[2][t] + ps[3][t];
}

// ---------------------------------------------------------------------------
extern "C" void kernel_launch(void* const* d_in, const int* in_sizes, int n_in,
                              void* d_out, int out_size, void* d_ws, size_t ws_size,
                              hipStream_t stream) {
  const float* x_aux = (const float*)d_in[0];
  const float* g1w = (const float*)d_in[1];
  const float* g1b = (const float*)d_in[2];
  const float* g2w = (const float*)d_in[3];
  const float* g2b = (const float*)d_in[4];
  const float* g3w = (const float*)d_in[5];
  const float* g3b = (const float*)d_in[6];
  const float* g4w = (const float*)d_in[7];
  const float* g4b = (const float*)d_in[8];
  const float* f1w = (const float*)d_in[9];
  const float* f1b = (const float*)d_in[10];
  const float* f2w = (const float*)d_in[11];
  const float* f2b = (const float*)d_in[12];
  const float* f3w = (const float*)d_in[13];
  const float* f3b = (const float*)d_in[14];
  float* out = (float*)d_out;

  _Float16* wtf = (_Float16*)d_ws;                                  // 512 KB
  float* xg  = (float*)((char*)d_ws + 512u * 1024u);                // 32 KB
  float* cib = (float*)((char*)d_ws + 544u * 1024u);                // 2 MB
  float* h0j = (float*)((char*)d_ws + 544u * 1024u + 2048u * 1024u);// 2 MB

  hipLaunchKernelGGL(prep_all, dim3(800), dim3(256), 0, stream,
                     x_aux, g1w, g1b, g2w, g3w, g4w, wtf, xg, cib, h0j);
  hipLaunchKernelGGL(g_mlp_pool, dim3(BATCH * 32), dim3(512), 0, stream,
                     h0j, cib, wtf, g2b, g3b, g4b, xg);
  hipLaunchKernelGGL(f_mlp, dim3(BATCH), dim3(1024), 0, stream,
                     xg, f1w, f1b, f2w, f2b, f3w, f3b, out);
}

// Round 2
// 152.836 us; speedup vs baseline: 1.0000x; 1.0000x over previous
//
#include <hip/hip_runtime.h>

#define BATCH 32
#define NOBJ  64
#define PADK  264   // halfs; A-tile row stride 528 B (16B-aligned)

typedef _Float16 f16x2 __attribute__((ext_vector_type(2)));
typedef __fp16   h16x2 __attribute__((ext_vector_type(2)));
typedef _Float16 f16x4 __attribute__((ext_vector_type(4)));
typedef _Float16 f16x8 __attribute__((ext_vector_type(8)));
typedef float    f32x4 __attribute__((ext_vector_type(4)));
typedef float    f32x16 __attribute__((ext_vector_type(16)));

#define MFMA32(a, b, c) __builtin_amdgcn_mfma_f32_32x32x16_f16((a), (b), (c), 0, 0, 0)

// ---------------------------------------------------------------------------
// Layer-0 is removed from the MFMA loop entirely (exact algebra):
//   h1[b][(i,j)][n] = relu( h0j[b][j][n] + cib[b][i][n] )
//   h0j = x_j·W0[0:64] + j·W0[64]          (per-batch, shared by all i)
//   cib = x_i·W0[65:193] + i·W0[193] + b1  (per-(b,i))
// Both fp32, computed in prep_all. g_mlp builds act1 directly and runs
// layers 1-3 (K=256, 16 steps each).
//
// R2: g_mlp waves reshaped Mt=2xNt=2 -> Mt=4xNt=1 (wave = one N-group,
// all 128 rows). R1 post-mortem: B-stream (wtf via L1/L2) was 512 B/MFMA
// = 20.5us/CU, exactly co-limiting with the MFMA pipe (20.5us) -- which
// is why 2x occupancy moved MfmaUtil only 37.7->39.4. Nt=1 reads B once
// per block (256 B/MFMA -> ~10us), MFMA becomes the sole dominant pipe.
// Side effect: no cross-group f16x2 pack -> activation LDS layout is now
// IDENTITY (As[row][n], b16 epilogue writes, <=2-way bank = free) and
// weight k-order is identity for ALL layers (prep_all simplified).
//
// Dispatches (3): prep_all (800 blocks), g_mlp_pool (1024x512), f_mlp (32).
// NO device-scope fences anywhere (r10 lesson: __threadfence = L2 flush).
// Simple in-loop loads (explicit dbuf regressed: m131-m141 precedent --
// compiler scheduling already optimal for this structure).
// ---------------------------------------------------------------------------

// ---------------------------------------------------------------------------
// Kernel 0: prep_all.
// blk 0..31  : zero xg; repack weights l=blk>>3 in MFMA B-fragment order
//              (skip l==0 -- unused):
//              wtf[l][ngrp=8][kk=16][lane=64][j=8] = W_l[k][nlog]
//              nlog = ngrp*32+(lane&31), k = kk*16+(lane>>5)*8+j
//              (identity k-order for all layers -- R2 plain act layout).
// blk 32..543: cib (per-(b, 4 i's)); thread t = col n.
// blk 544..799: h0j (per-(b, 8 j's)); thread t = col n.
// ---------------------------------------------------------------------------
__global__ __launch_bounds__(256) void prep_all(
    const float* __restrict__ x_aux,
    const float* __restrict__ g1w, const float* __restrict__ g1b,
    const float* __restrict__ g2w, const float* __restrict__ g3w,
    const float* __restrict__ g4w,
    _Float16* __restrict__ wtf, float* __restrict__ xg,
    float* __restrict__ cib, float* __restrict__ h0j) {
  __shared__ __align__(16) _Float16 tile[256][33];
  const int blk = blockIdx.x;
  const int t = threadIdx.x;

  if (blk < 32) {
    xg[blk * 256 + t] = 0.0f;
    const int l = blk >> 3;
    if (l == 0) return;                 // layer-0 weights not needed
    const int nt = blk & 7;
    const float* src = (l == 1) ? g2w : (l == 2) ? g3w : g4w;

    const int nn = t & 31, kb = t >> 5;
#pragma unroll 4
    for (int pass = 0; pass < 32; ++pass) {
      int kp = pass * 8 + kb;
      tile[kp][nn] = (_Float16)src[(size_t)kp * 256 + nt * 32 + nn];
    }
    __syncthreads();

    const int lane = t & 63;
    const int nfrag = lane & 31;
    const int kbase = (lane >> 5) * 8;
    _Float16* dst = wtf + ((size_t)(l * 8 + nt) * 16) * 512;
#pragma unroll
    for (int q = 0; q < 4; ++q) {
      int kk = (t >> 6) + 4 * q;
      f16x8 fr;
#pragma unroll
      for (int j = 0; j < 8; ++j)
        fr[j] = tile[kk * 16 + kbase + j][nfrag];
      *(f16x8*)(dst + (size_t)kk * 512 + lane * 8) = fr;
    }
  } else if (blk < 544) {
    // ---- cib = x_i . W0[65:193] + i*W0[193] + b1  (fp32) ----
    float* xs = (float*)&tile[0][0];     // [4][128]
    const int blkc = blk - 32;           // 512 = 32 b x 16 groups
    const int b  = blkc >> 4;
    const int i0 = (blkc & 15) * 4;

#pragma unroll
    for (int u = 0; u < 2; ++u) {
      int idx = u * 256 + t;
      int j = idx >> 7, k = idx & 127;
      xs[j * 128 + k] = x_aux[((size_t)(b * NOBJ + i0 + j)) * 128 + k];
    }
    __syncthreads();

    float c0 = 0.f, c1 = 0.f, c2 = 0.f, c3 = 0.f;
#pragma unroll 2
    for (int k = 0; k < 128; k += 4) {
      f32x4 x0 = *(const f32x4*)&xs[k];
      f32x4 x1 = *(const f32x4*)&xs[128 + k];
      f32x4 x2 = *(const f32x4*)&xs[256 + k];
      f32x4 x3 = *(const f32x4*)&xs[384 + k];
#pragma unroll
      for (int q = 0; q < 4; ++q) {
        float w = g1w[(size_t)(65 + k + q) * 256 + t];
        c0 += x0[q] * w; c1 += x1[q] * w;
        c2 += x2[q] * w; c3 += x3[q] * w;
      }
    }
    float wc = g1w[(size_t)193 * 256 + t];
    float bb = g1b[t];
    c0 += (float)(i0 + 0) * wc + bb;
    c1 += (float)(i0 + 1) * wc + bb;
    c2 += (float)(i0 + 2) * wc + bb;
    c3 += (float)(i0 + 3) * wc + bb;
    cib[((size_t)(b * NOBJ + i0 + 0)) * 256 + t] = c0;
    cib[((size_t)(b * NOBJ + i0 + 1)) * 256 + t] = c1;
    cib[((size_t)(b * NOBJ + i0 + 2)) * 256 + t] = c2;
    cib[((size_t)(b * NOBJ + i0 + 3)) * 256 + t] = c3;
  } else {
    // ---- h0j = x_j . W0[0:64] + j*W0[64]  (fp32, no bias) ----
    // stride-68 rows so f32x4 reads are 16B-aligned; coord handled in regs.
    float* xs = (float*)&tile[0][0];     // [8][68]
    const int blk2 = blk - 544;          // 256 = 32 b x 8 jgroups
    const int b  = blk2 >> 3;
    const int j0 = (blk2 & 7) * 8;

#pragma unroll
    for (int u = 0; u < 2; ++u) {
      int idx = u * 256 + t;             // 0..511
      int jj = idx >> 6, k = idx & 63;
      xs[jj * 68 + k] = x_aux[((size_t)(b * NOBJ + j0 + jj)) * 128 + k];
    }
    __syncthreads();

    float acc[8] = {};
#pragma unroll 2
    for (int k = 0; k < 64; k += 4) {
      f32x4 xv[8];
#pragma unroll
      for (int jj = 0; jj < 8; ++jj)
        xv[jj] = *(const f32x4*)&xs[jj * 68 + k];
#pragma unroll
      for (int q = 0; q < 4; ++q) {
        float w = g1w[(size_t)(k + q) * 256 + t];
#pragma unroll
        for (int jj = 0; jj < 8; ++jj) acc[jj] += xv[jj][q] * w;
      }
    }
    float wc = g1w[(size_t)64 * 256 + t];   // coord column
#pragma unroll
    for (int jj = 0; jj < 8; ++jj)
      h0j[((size_t)(b * NOBJ + j0 + jj)) * 256 + t] =
          acc[jj] + (float)(j0 + jj) * wc;
  }
}

// ---------------------------------------------------------------------------
// Kernel 1: fused g-MLP layers 1-3 + sum-pool for TWO i's per block.
// Block = 512 thr (8 waves). M=128 (2 i's x 64 j), N=256, K=256.
// Tile build: act1[m][n] = relu(h0j[j] + cib[i]) -- coalesced (1 KB row
// per wave instruction), h0j row read once for both i-halves.
// Wave wv = N-group (0..7, 32 cols each), Mt=4 (all 128 rows): B-frag
// read ONCE per block per layer (256 B/MFMA -- R1's Mt=2xNt=2 was
// 512 B/MFMA and the vmem return path co-limited with the MFMA pipe).
// acc = 4 x f32x16 = 64 VGPR -> 2 blocks/CU = 4 waves/SIMD.
// ---------------------------------------------------------------------------
__global__ __launch_bounds__(512, 4) void g_mlp_pool(
    const float* __restrict__ h0j,            // [B*64][256] fp32
    const float* __restrict__ cib,            // [B*64][256] fp32
    const _Float16* __restrict__ wtf,         // fragment-ordered
    const float* __restrict__ g2b, const float* __restrict__ g3b,
    const float* __restrict__ g4b,
    float* __restrict__ xg) {                 // [B][256] fp32 (pre-zeroed)
  __shared__ __align__(16) _Float16 As[128][PADK];  // 67.6 KB -> 2 blocks/CU

  const int b  = blockIdx.x >> 5;
  const int i0 = (blockIdx.x & 31) * 2;
  const int t  = threadIdx.x;
  const int lane = t & 63;
  const int wv   = t >> 6;                    // 0..7 = this wave's N-group

  // ---- build act1 tile: rows j and 64+j share the same h0j row ----
  {
    const int c = lane * 4;                   // this lane's 4 cols
    const float* hb = h0j + (size_t)(b * NOBJ) * 256 + c;
    const float* c0p = cib + (size_t)(b * NOBJ + i0) * 256 + c;
    f32x4 cv0 = *(const f32x4*)c0p;
    f32x4 cv1 = *(const f32x4*)(c0p + 256);
#pragma unroll
    for (int it = 0; it < 8; ++it) {
      int j = it * 8 + wv;
      f32x4 hv = *(const f32x4*)(hb + (size_t)j * 256);
      f16x4 p0, p1;
#pragma unroll
      for (int q = 0; q < 4; ++q) {
        p0[q] = (_Float16)fmaxf(hv[q] + cv0[q], 0.f);
        p1[q] = (_Float16)fmaxf(hv[q] + cv1[q], 0.f);
      }
      *(f16x4*)&As[j][c]      = p0;
      *(f16x4*)&As[64 + j][c] = p1;
    }
  }
  __syncthreads();

  const int c31  = lane & 31;
  const int h    = lane >> 5;       // 0/1 (k-half of the A/B fragments)
  const int n0   = wv * 32;
  const float* gb[4] = {nullptr, g2b, g3b, g4b};

  for (int layer = 1; layer < 4; ++layer) {
    const float bv = gb[layer][n0 + c31];

    f32x16 acc[4];   // [m]
#pragma unroll
    for (int x = 0; x < 4; ++x) acc[x] = (f32x16){};

    const _Float16* bp =
        wtf + ((size_t)(layer * 8 + wv) * 16) * 512 + lane * 8;
    const _Float16* arow = &As[c31][h * 8];

#pragma unroll
    for (int kk = 0; kk < 16; ++kk) {
      f16x8 bfr = *(const f16x8*)(bp + (size_t)kk * 512);
#pragma unroll
      for (int m = 0; m < 4; ++m) {
        f16x8 a = *(const f16x8*)(arow + (size_t)m * 32 * PADK + kk * 16);
        acc[m] = MFMA32(a, bfr, acc[m]);
      }
    }

    if (layer < 3) {
      __syncthreads();   // all waves done reading As
      // C/D layout: col = lane&31, row = (reg&3) + 8*(reg>>2) + 4*h.
      // Identity act layout: As[row][n0+c31], plain b16 stores.
      // Lanes c,c+1 share a dword (byte halves) and h=0/h=1 hit disjoint
      // 16-bank halves (row diff 4 -> +16 banks): <=2-way = free (m136).
#pragma unroll
      for (int m = 0; m < 4; ++m)
#pragma unroll
        for (int g = 0; g < 4; ++g)
#pragma unroll
          for (int r = 0; r < 4; ++r) {
            const int row = m * 32 + g * 8 + h * 4 + r;
            As[row][n0 + c31] = (_Float16)fmaxf(acc[m][g * 4 + r] + bv, 0.f);
          }
      __syncthreads();
    } else {
      // layer 4: bias + relu + pool; each lane sums its 64 rows (h-half),
      // shfl_xor(32) folds the two halves -> full 128-row sum per col.
      float s = 0.f;
#pragma unroll
      for (int m = 0; m < 4; ++m)
#pragma unroll
        for (int reg = 0; reg < 16; ++reg)
          s += fmaxf(acc[m][reg] + bv, 0.f);
      s += __shfl_xor(s, 32, 64);
      if (h == 0) atomicAdd(&xg[b * 256 + n0 + c31], s);
    }
  }
}

// ---------------------------------------------------------------------------
// Kernel 2: f-MLP. One block per batch, 1024 threads: n = t&255 owns column,
// kc = t>>8 owns a 64-wide k-chunk; LDS reduce the 4 partials per column.
// ---------------------------------------------------------------------------
__global__ __launch_bounds__(1024) void f_mlp(
    const float* __restrict__ xg,
    const float* __restrict__ f1w, const float* __restrict__ f1b,
    const float* __restrict__ f2w, const float* __restrict__ f2b,
    const float* __restrict__ f3w, const float* __restrict__ f3b,
    float* __restrict__ out) {
  __shared__ float xs[256], ys[256], ps[4][256];
  const int b = blockIdx.x;
  const int t = threadIdx.x;
  const int n = t & 255;
  const int kc = t >> 8;

  if (t < 256) xs[t] = xg[b * 256 + t];
  __syncthreads();

  float p = 0.f;
#pragma unroll 8
  for (int k0 = 0; k0 < 64; ++k0) {
    int k = kc * 64 + k0;
    p += xs[k] * f1w[k * 256 + n];
  }
  ps[kc][n] = p;
  __syncthreads();
  if (t < 256)
    ys[t] = fmaxf(f1b[t] + ps[0][t] + ps[1][t] + ps[2][t] + ps[3][t], 0.f);
  __syncthreads();

  p = 0.f;
#pragma unroll 8
  for (int k0 = 0; k0 < 64; ++k0) {
    int k = kc * 64 + k0;
    p += ys[k] * f2w[k * 256 + n];
  }
  ps[kc][n] = p;
  __syncthreads();
  if (t < 256)
    xs[t] = fmaxf(f2b[t] + ps[0][t] + ps[1][t] + ps[2][t] + ps[3][t], 0.f);
  __syncthreads();

  p = 0.f;
#pragma unroll 8
  for (int k0 = 0; k0 < 64; ++k0) {
    int k = kc * 64 + k0;
    p += xs[k] * f3w[k * 256 + n];
  }
  ps[kc][n] = p;
  __syncthreads();
  if (t < 256)
    out[b * 256 + t] = f3b[t] + ps[0][t] + ps[1][t] + ps[2][t] + ps[3][t];
}

// ---------------------------------------------------------------------------
extern "C" void kernel_launch(void* const* d_in, const int* in_sizes, int n_in,
                              void* d_out, int out_size, void* d_ws, size_t ws_size,
                              hipStream_t stream) {
  const float* x_aux = (const float*)d_in[0];
  const float* g1w = (const float*)d_in[1];
  const float* g1b = (const float*)d_in[2];
  const float* g2w = (const float*)d_in[3];
  const float* g2b = (const float*)d_in[4];
  const float* g3w = (const float*)d_in[5];
  const float* g3b = (const float*)d_in[6];
  const float* g4w = (const float*)d_in[7];
  const float* g4b = (const float*)d_in[8];
  const float* f1w = (const float*)d_in[9];
  const float* f1b = (const float*)d_in[10];
  const float* f2w = (const float*)d_in[11];
  const float* f2b = (const float*)d_in[12];
  const float* f3w = (const float*)d_in[13];
  const float* f3b = (const float*)d_in[14];
  float* out = (float*)d_out;

  _Float16* wtf = (_Float16*)d_ws;                                  // 512 KB
  float* xg  = (float*)((char*)d_ws + 512u * 1024u);                // 32 KB
  float* cib = (float*)((char*)d_ws + 544u * 1024u);                // 2 MB
  float* h0j = (float*)((char*)d_ws + 544u * 1024u + 2048u * 1024u);// 2 MB

  hipLaunchKernelGGL(prep_all, dim3(800), dim3(256), 0, stream,
                     x_aux, g1w, g1b, g2w, g3w, g4w, wtf, xg, cib, h0j);
  hipLaunchKernelGGL(g_mlp_pool, dim3(BATCH * 32), dim3(512), 0, stream,
                     h0j, cib, wtf, g2b, g3b, g4b, xg);
  hipLaunchKernelGGL(f_mlp, dim3(BATCH), dim3(1024), 0, stream,
                     xg, f1w, f1b, f2w, f2b, f3w, f3b, out);
}